// Round 11
// baseline (247.086 us; speedup 1.0000x reference)
//
#include <hip/hip_runtime.h>

#define D 128
#define N_GRAPHS 64

typedef unsigned int uint32;
typedef __attribute__((ext_vector_type(8))) _Float16 f16x8;
typedef __attribute__((ext_vector_type(4))) float f32x4;

// fp16 helpers: dword holds 2 fp16 (low = elem 2i, high = elem 2i+1); RNE cvt
__device__ __forceinline__ float hl(uint32 u) {
    return (float)__builtin_bit_cast(_Float16, (unsigned short)(u & 0xFFFF));
}
__device__ __forceinline__ float hh(uint32 u) {
    return (float)__builtin_bit_cast(_Float16, (unsigned short)(u >> 16));
}
__device__ __forceinline__ uint32 h2pair(float a, float b) {
    unsigned short ua = __builtin_bit_cast(unsigned short, (_Float16)a);
    unsigned short ub = __builtin_bit_cast(unsigned short, (_Float16)b);
    return (uint32)ua | ((uint32)ub << 16);
}

// ---------------- CSR build ----------------

// count in-degree AND capture each edge's rank among its dst's edges.
// (R9 lesson: folding this atomic into fill puts the RMW return on the
// scatter's critical path — fill went 40 -> 67 us. Keep it split.)
__global__ void count_rank_kernel(const int* __restrict__ dst, int* __restrict__ cnt,
                                  int* __restrict__ rank, int E) {
    int e = blockIdx.x * blockDim.x + threadIdx.x;
    if (e < E) rank[e] = atomicAdd(&cnt[dst[e]], 1);
}

// parallel scan, phase A. Fused: dinv; coalesced zeroing of this block's c rows
// + self-loop term c[i][batch[i]] = dinv_i^2 (ordered by the block barrier).
__global__ __launch_bounds__(1024) void scanA_kernel(const int* __restrict__ cnt,
                                                     int* __restrict__ rowptr,
                                                     int* __restrict__ tot,
                                                     float* __restrict__ dinv,
                                                     float* __restrict__ c,
                                                     const int* __restrict__ batch, int n) {
    __shared__ int swave[16];
    int t = threadIdx.x;
    int lane = t & 63, wave = t >> 6;
    int i = blockIdx.x * 1024 + t;
    // coalesced zero of c rows [blockIdx*1024, +1024) — replaces a 10.24MB memset
    {
        size_t f4base = (size_t)blockIdx.x * 1024 * 16;  // 16 float4 per 64-float row
        size_t f4lim = (size_t)n * 16;
        float4 z = make_float4(0.f, 0.f, 0.f, 0.f);
#pragma unroll
        for (int q = 0; q < 16; ++q) {
            size_t idx = f4base + (size_t)q * 1024 + t;
            if (idx < f4lim) ((float4*)c)[idx] = z;
        }
    }
    int orig = (i < n) ? cnt[i] : 0;
    int v = orig;
#pragma unroll
    for (int off = 1; off < 64; off <<= 1) {
        int u = __shfl_up(v, off, 64);
        if (lane >= off) v += u;
    }
    if (lane == 63) swave[wave] = v;
    __syncthreads();  // orders c-zeroing before the slot store below too
    if (wave == 0) {
        int wv = (lane < 16) ? swave[lane] : 0;
#pragma unroll
        for (int off = 1; off < 16; off <<= 1) {
            int u = __shfl_up(wv, off, 64);
            if (lane >= off) wv += u;
        }
        if (lane < 16) swave[lane] = wv;
    }
    if (i < n) {
        float dv = rsqrtf((float)(orig + 1));  // deg = in-deg + self loop
        dinv[i] = dv;
        c[(size_t)i * N_GRAPHS + batch[i]] = dv * dv;  // self-loop contribution
    }
    __syncthreads();
    int incl = v + ((wave > 0) ? swave[wave - 1] : 0);
    if (i < n) rowptr[i] = incl - orig;  // chunk-local exclusive
    if (t == 1023) tot[blockIdx.x] = incl;
}

// phase B: add chunk offsets (<=40 totals: serial per-block prefix is cheap)
__global__ __launch_bounds__(1024) void scanB_kernel(int* __restrict__ rowptr,
                                                     const int* __restrict__ tot,
                                                     int n, int nchunks) {
    __shared__ int soff;
    int b = blockIdx.x, t = threadIdx.x;
    if (t == 0) {
        int o = 0;
        for (int j = 0; j < b; ++j) o += tot[j];
        soff = o;
    }
    __syncthreads();
    int i = b * 1024 + t;
    if (i < n) rowptr[i] += soff;
    if (b == 0 && t == 0) {
        int o = 0;
        for (int j = 0; j < nchunks; ++j) o += tot[j];
        rowptr[n] = o;
    }
}

// scatter col only (4B — w is recomputed in agg from L2-resident dinv), and
// accumulate the edge term of c: c[src][batch[dst]] += w
__global__ void fill_kernel(const int* __restrict__ src, const int* __restrict__ dst,
                            const int* __restrict__ rowptr, const int* __restrict__ rank,
                            int* __restrict__ col,
                            const float* __restrict__ dinv,
                            float* __restrict__ c, const int* __restrict__ batch, int E) {
    int e = blockIdx.x * blockDim.x + threadIdx.x;
    if (e < E) {
        int s = src[e], d = dst[e];
        int pos = rowptr[d] + rank[e];
        col[pos] = s;
        float w = dinv[s] * dinv[d];
        atomicAdd(&c[(size_t)s * N_GRAPHS + batch[d]], w);
    }
}

// ---------------- MFMA fp16 GEMM: hb[M x 128](fp16) = fp16(A) @ fp16(W) ----------
// 64-row x 128-col block, 4 waves each 32x64. fp32->fp16 conversion fused into
// LDS staging. LDS rows padded to 136 fp16 (68 dw): frag reads are 2-way max.
// Fragment layouts (m89/m120-verified, dtype-independent): A[m=lane&15][k=quad*8+j],
// B[k=quad*8+j][n=lane&15] (W transposed in LDS), C/D col=lane&15, row=quad*4+reg.

#define GBM 64

__global__ __launch_bounds__(256) void mfma_gemm_kernel(const float* __restrict__ A,
                                                        const float* __restrict__ W,
                                                        uint32* __restrict__ hb, int M) {
    __shared__ uint32 lds[64 * 68 + 128 * 68];  // As 17408B + Wt 34816B = 52224B
    uint32* As = lds;             // [64 rows][68 dw]
    uint32* Wt = lds + 64 * 68;   // [128 n][68 dw] — W transposed
    int tid = threadIdx.x;
    int row0 = blockIdx.x * GBM;

    // stage A tile: 64x128 fp32 -> fp16 (2048 float4, 8/thread, coalesced)
#pragma unroll
    for (int j = 0; j < 8; ++j) {
        int idx = tid + j * 256;
        int r = idx >> 5, c4 = idx & 31;
        float4 v = make_float4(0.f, 0.f, 0.f, 0.f);
        if (row0 + r < M) v = *(const float4*)&A[(size_t)(row0 + r) * D + c4 * 4];
        As[r * 68 + c4 * 2 + 0] = h2pair(v.x, v.y);
        As[r * 68 + c4 * 2 + 1] = h2pair(v.z, v.w);
    }
    // stage W^T: thread owns column n, half the k range (lane-coalesced global reads)
    {
        int nn = tid & 127, half = tid >> 7;
        int kbase = half * 64;
#pragma unroll
        for (int kk = 0; kk < 64; kk += 2) {
            float v0 = W[(size_t)(kbase + kk) * D + nn];
            float v1 = W[(size_t)(kbase + kk + 1) * D + nn];
            Wt[nn * 68 + ((kbase + kk) >> 1)] = h2pair(v0, v1);
        }
    }
    __syncthreads();

    int wave = tid >> 6, lane = tid & 63;
    int quad = lane >> 4, l16 = lane & 15;
    int wr = (wave & 1) * 32;   // wave row base (2 m-tiles)
    int wc = (wave >> 1) * 64;  // wave col base (4 n-tiles)
    f32x4 acc[2][4];
#pragma unroll
    for (int mi = 0; mi < 2; ++mi)
#pragma unroll
        for (int ni = 0; ni < 4; ++ni) acc[mi][ni] = (f32x4){0.f, 0.f, 0.f, 0.f};

#pragma unroll
    for (int ks = 0; ks < 4; ++ks) {
        int kd = ks * 16 + quad * 4;  // dword offset of k0 + quad*8 fp16
        f16x8 a0 = *(f16x8*)&As[(wr + l16) * 68 + kd];
        f16x8 a1 = *(f16x8*)&As[(wr + 16 + l16) * 68 + kd];
        f16x8 b0 = *(f16x8*)&Wt[(wc + l16) * 68 + kd];
        f16x8 b1 = *(f16x8*)&Wt[(wc + 16 + l16) * 68 + kd];
        f16x8 b2 = *(f16x8*)&Wt[(wc + 32 + l16) * 68 + kd];
        f16x8 b3 = *(f16x8*)&Wt[(wc + 48 + l16) * 68 + kd];
        acc[0][0] = __builtin_amdgcn_mfma_f32_16x16x32_f16(a0, b0, acc[0][0], 0, 0, 0);
        acc[0][1] = __builtin_amdgcn_mfma_f32_16x16x32_f16(a0, b1, acc[0][1], 0, 0, 0);
        acc[0][2] = __builtin_amdgcn_mfma_f32_16x16x32_f16(a0, b2, acc[0][2], 0, 0, 0);
        acc[0][3] = __builtin_amdgcn_mfma_f32_16x16x32_f16(a0, b3, acc[0][3], 0, 0, 0);
        acc[1][0] = __builtin_amdgcn_mfma_f32_16x16x32_f16(a1, b0, acc[1][0], 0, 0, 0);
        acc[1][1] = __builtin_amdgcn_mfma_f32_16x16x32_f16(a1, b1, acc[1][1], 0, 0, 0);
        acc[1][2] = __builtin_amdgcn_mfma_f32_16x16x32_f16(a1, b2, acc[1][2], 0, 0, 0);
        acc[1][3] = __builtin_amdgcn_mfma_f32_16x16x32_f16(a1, b3, acc[1][3], 0, 0, 0);
    }
    __syncthreads();  // done reading As/Wt; reuse As region as C staging [64][128] fp16

    unsigned short* cs = (unsigned short*)lds;
#pragma unroll
    for (int mi = 0; mi < 2; ++mi)
#pragma unroll
        for (int ni = 0; ni < 4; ++ni)
#pragma unroll
            for (int r = 0; r < 4; ++r) {
                int row = wr + mi * 16 + quad * 4 + r;
                int col = wc + ni * 16 + l16;
                cs[row * 128 + col] =
                    __builtin_bit_cast(unsigned short, (_Float16)acc[mi][ni][r]);
            }
    __syncthreads();
    // coalesced write-out: 64 rows x 16 uint4; C-staging row = 128 fp16 = 64 dwords
#pragma unroll
    for (int j = 0; j < 4; ++j) {
        int idx = tid + j * 256;
        int r = idx >> 4, q = idx & 15;
        if (row0 + r < M)
            *(uint4*)&hb[(size_t)(row0 + r) * 64 + q * 4] = *(uint4*)&lds[r * 64 + q * 4];
    }
}

// ---------------- aggregation (gather over CSR) + bias + ReLU -> fp16 H1 --------
// FEATURE-SPLIT: two passes, each gathering a 128B half-row (32 lanes x 1 dword).
// Per-XCD gathered working set per pass = 2.56MB < 4MiB L2 -> gathers become L2
// hits instead of L2 fills (agg's FETCH was ~8x the feature matrix = per-XCD L2
// fill traffic). col/dinv re-read per pass is only ~3MB. w recomputed on the fly.

__global__ __launch_bounds__(128) void agg_half_kernel(const uint32* __restrict__ hb,
                                                       const int* __restrict__ rowptr,
                                                       const int* __restrict__ col,
                                                       const float* __restrict__ dinv,
                                                       const float* __restrict__ bias,
                                                       uint32* __restrict__ h1, int n,
                                                       int half) {
    int tid = threadIdx.x;
    int lane32 = tid & 31;   // dword within half-row
    int slot = tid >> 5;     // 0..3
    int node = blockIdx.x * 4 + slot;
    if (node >= n) return;
    int dw = half * 32 + lane32;          // dword index in the 64-dword row
    float2 bp = ((const float2*)bias)[dw];  // features 2*dw, 2*dw+1

    float di = dinv[node];
    float ws = di * di;
    uint32 su = hb[(size_t)node * 64 + dw];
    float a0 = ws * hl(su), a1 = ws * hh(su);

    int k = rowptr[node], end = rowptr[node + 1];
    for (; k + 8 <= end; k += 8) {
        uint32 v[8];
        float w[8];
#pragma unroll
        for (int j = 0; j < 8; ++j) {
            int s = col[k + j];
            w[j] = dinv[s] * di;
            v[j] = hb[(size_t)s * 64 + dw];
        }
#pragma unroll
        for (int j = 0; j < 8; ++j) {
            a0 = fmaf(w[j], hl(v[j]), a0);
            a1 = fmaf(w[j], hh(v[j]), a1);
        }
    }
    for (; k < end; ++k) {
        int s = col[k];
        float w = dinv[s] * di;
        uint32 v = hb[(size_t)s * 64 + dw];
        a0 = fmaf(w, hl(v), a0);
        a1 = fmaf(w, hh(v), a1);
    }

    a0 = fmaxf(a0 + bp.x, 0.f);
    a1 = fmaxf(a1 + bp.y, 0.f);
    h1[(size_t)node * 64 + dw] = h2pair(a0, a1);
}

// ---------------- pooled layer 2: out = rinv * (c^T H1) W2 + b2 ----------------

// Gp partials: Ppart[b][g][f] = sum_{j in block b's range} c[j][g] * H1[j][f]
#define GP_NB 128
#define GP_T 16

__global__ __launch_bounds__(256) void gp_kernel(const float* __restrict__ c,
                                                 const uint32* __restrict__ H1,
                                                 float* __restrict__ Ppart, int n) {
    __shared__ float sc[GP_T][N_GRAPHS];
    __shared__ uint32 sh[GP_T][64];  // fp16 pairs: 128 feats = 64 dwords
    int t = threadIdx.x;
    int b = blockIdx.x;
    int jpb = (n + GP_NB - 1) / GP_NB;
    int j0 = b * jpb;
    int j1 = min(j0 + jpb, n);
    int g0 = (t & 7) * 8;    // 8 graphs per thread
    int f0 = (t >> 3) * 4;   // 4 feats per thread (dwords f0/2, f0/2+1)
    float acc[8][4];
#pragma unroll
    for (int a = 0; a < 8; ++a)
#pragma unroll
        for (int q = 0; q < 4; ++q) acc[a][q] = 0.f;

    for (int jt = j0; jt < j1; jt += GP_T) {
        int cnt = min(GP_T, j1 - jt);
        // stage c tile: GP_T x 64 floats = 256 float4, 1/thread
        {
            int r = t >> 4, q = t & 15;
            float4 v = (r < cnt) ? *(const float4*)&c[(size_t)(jt + r) * N_GRAPHS + q * 4]
                                 : make_float4(0.f, 0.f, 0.f, 0.f);
            *(float4*)&sc[r][q * 4] = v;
        }
        // stage H1 fp16 tile: GP_T rows x 16 uint4 = 256, 1/thread
        {
            int r = t >> 4, q = t & 15;
            uint4 v = make_uint4(0, 0, 0, 0);
            if (r < cnt) v = *(const uint4*)&H1[(size_t)(jt + r) * 64 + q * 4];
            *(uint4*)&sh[r][q * 4] = v;
        }
        __syncthreads();
#pragma unroll
        for (int r = 0; r < GP_T; ++r) {  // zero-padded rows contribute 0
            float cw[8], hv[4];
            *(float4*)&cw[0] = *(float4*)&sc[r][g0];
            *(float4*)&cw[4] = *(float4*)&sc[r][g0 + 4];
            uint32 u0 = sh[r][f0 >> 1], u1 = sh[r][(f0 >> 1) + 1];
            hv[0] = hl(u0); hv[1] = hh(u0); hv[2] = hl(u1); hv[3] = hh(u1);
#pragma unroll
            for (int a = 0; a < 8; ++a)
#pragma unroll
                for (int q = 0; q < 4; ++q) acc[a][q] = fmaf(cw[a], hv[q], acc[a][q]);
        }
        __syncthreads();
    }
    float* P = &Ppart[(size_t)b * N_GRAPHS * D];
#pragma unroll
    for (int a = 0; a < 8; ++a)
        *(float4*)&P[(size_t)(g0 + a) * D + f0] =
            make_float4(acc[a][0], acc[a][1], acc[a][2], acc[a][3]);
}

// epilogue: out[g][f] = rinv_g * sum_k (sum_b Ppart[b][g][k]) * W2[k][f] + b2[f]
// rinv computed in-block via binary search on sorted batch (graph_count folded in)
__global__ __launch_bounds__(128) void out_kernel(const float* __restrict__ Ppart,
                                                  const float* __restrict__ W2,
                                                  const float* __restrict__ b2,
                                                  const int* __restrict__ batch, int n,
                                                  float* __restrict__ out) {
    __shared__ float gs[D];
    __shared__ float srinv;
    int g = blockIdx.x, f = threadIdx.x;
    if (f == 0) {
        int lo = 0, hi = n;
        while (lo < hi) { int mid = (lo + hi) >> 1; if (batch[mid] < g) lo = mid + 1; else hi = mid; }
        int lb = lo;
        int g1 = g + 1;
        lo = 0; hi = n;
        while (lo < hi) { int mid = (lo + hi) >> 1; if (batch[mid] < g1) lo = mid + 1; else hi = mid; }
        int cg = lo - lb;
        srinv = (cg > 0) ? 1.0f / (float)cg : 0.0f;
    }
    float s = 0.f;
    for (int b = 0; b < GP_NB; ++b) s += Ppart[((size_t)b * N_GRAPHS + g) * D + f];
    gs[f] = s;
    __syncthreads();
    float acc = 0.f;
#pragma unroll 8
    for (int k = 0; k < D; ++k) acc = fmaf(gs[k], W2[k * D + f], acc);
    float r = srinv;
    out[g * D + f] = (r > 0.f) ? fmaf(acc, r, b2[f]) : 0.f;  // empty graph -> 0 (matches ref)
}

// ---------------- launcher ----------------

extern "C" void kernel_launch(void* const* d_in, const int* in_sizes, int n_in,
                              void* d_out, int out_size, void* d_ws, size_t ws_size,
                              hipStream_t stream) {
    const float* x  = (const float*)d_in[0];
    const int*   ei = (const int*)d_in[1];
    const int*   batch = (const int*)d_in[2];
    const float* W1 = (const float*)d_in[3];
    const float* b1 = (const float*)d_in[4];
    const float* W2 = (const float*)d_in[5];
    const float* b2 = (const float*)d_in[6];
    float* out = (float*)d_out;

    const int n = in_sizes[2];       // 40000 nodes
    const int E = in_sizes[1] / 2;   // 640000 edges
    const int* src = ei;             // edge_index[0] = message sources
    const int* dst = ei + E;         // edge_index[1] = aggregation targets

    // workspace carve-up (256B aligned)
    char* ws = (char*)d_ws;
    size_t off = 0;
    auto carve = [&](size_t bytes) {
        size_t o = off;
        off = (off + bytes + 255) & ~(size_t)255;
        return (void*)(ws + o);
    };
    int*    cnt    = (int*)carve((size_t)n * 4);
    int*    rowptr = (int*)carve((size_t)(n + 1) * 4);
    float*  dinv   = (float*)carve((size_t)n * 4);
    int*    col    = (int*)carve((size_t)E * 4);                 // CSR col (2.56MB)
    uint32* hb     = (uint32*)carve((size_t)n * D * 2);          // fp16 feature rows (10.24MB)
    uint32* h1     = (uint32*)carve((size_t)n * D * 2);          // fp16 H1 rows (10.24MB)
    float*  c      = (float*)carve((size_t)n * N_GRAPHS * 4);    // pooled coeffs (10.24MB)
    int*    tot    = (int*)carve(64 * 4);
    // aliases into hb (10.24MB): rank (2.56MB, dead after fill — gemm1 writes hb after);
    // Ppart (4MB, written by gp after agg's last read of hb)
    int*    rank   = (int*)hb;
    float*  Ppart  = (float*)hb;
    (void)ws_size;

    const int nchunks = (n + 1023) >> 10;

    // zero-init (ws is poisoned 0xAA before every call); c zeroing fused into scanA
    hipMemsetAsync(cnt, 0, (size_t)n * 4, stream);

    // CSR build + pooled-coefficient matrix c (shared by both layers)
    count_rank_kernel<<<(E + 255) / 256, 256, 0, stream>>>(dst, cnt, rank, E);
    scanA_kernel<<<nchunks, 1024, 0, stream>>>(cnt, rowptr, tot, dinv, c, batch, n);
    scanB_kernel<<<nchunks, 1024, 0, stream>>>(rowptr, tot, n, nchunks);
    fill_kernel<<<(E + 255) / 256, 256, 0, stream>>>(src, dst, rowptr, rank, col, dinv, c, batch, E);

    // layer 1: hb = fp16(x @ W1) via MFMA ; agg + b1 + ReLU -> h1 (fp16),
    // feature-split into two L2-resident passes
    mfma_gemm_kernel<<<(n + GBM - 1) / GBM, 256, 0, stream>>>(x, W1, hb, n);
    agg_half_kernel<<<(n + 3) / 4, 128, 0, stream>>>(hb, rowptr, col, dinv, b1, h1, n, 0);
    agg_half_kernel<<<(n + 3) / 4, 128, 0, stream>>>(hb, rowptr, col, dinv, b1, h1, n, 1);

    // layer 2 + pool, algebraically fused: out = rinv * (c^T H1) W2 + b2
    gp_kernel<<<GP_NB, 256, 0, stream>>>(c, h1, Ppart, n);
    out_kernel<<<N_GRAPHS, 128, 0, stream>>>(Ppart, W2, b2, batch, n, out);
}

// Round 12
// 240.652 us; speedup vs baseline: 1.0267x; 1.0267x over previous
//
#include <hip/hip_runtime.h>

#define D 128
#define N_GRAPHS 64

typedef unsigned int uint32;
typedef __attribute__((ext_vector_type(8))) _Float16 f16x8;
typedef __attribute__((ext_vector_type(4))) float f32x4;

// fp16 helpers: dword holds 2 fp16 (low = elem 2i, high = elem 2i+1); RNE cvt
__device__ __forceinline__ float hl(uint32 u) {
    return (float)__builtin_bit_cast(_Float16, (unsigned short)(u & 0xFFFF));
}
__device__ __forceinline__ float hh(uint32 u) {
    return (float)__builtin_bit_cast(_Float16, (unsigned short)(u >> 16));
}
__device__ __forceinline__ uint32 h2pair(float a, float b) {
    unsigned short ua = __builtin_bit_cast(unsigned short, (_Float16)a);
    unsigned short ub = __builtin_bit_cast(unsigned short, (_Float16)b);
    return (uint32)ua | ((uint32)ub << 16);
}

// ---------------- CSR build ----------------

// count in-degree AND capture each edge's rank among its dst's edges.
// (R9 lesson: folding this atomic into fill puts the RMW return on the
// scatter's critical path — fill went 40 -> 67 us. Keep it split.)
__global__ void count_rank_kernel(const int* __restrict__ dst, int* __restrict__ cnt,
                                  int* __restrict__ rank, int E) {
    int e = blockIdx.x * blockDim.x + threadIdx.x;
    if (e < E) rank[e] = atomicAdd(&cnt[dst[e]], 1);
}

// parallel scan, phase A. Fused: dinv; coalesced zeroing of this block's c rows
// + self-loop term c[i][batch[i]] = dinv_i^2 (ordered by the block barrier).
__global__ __launch_bounds__(1024) void scanA_kernel(const int* __restrict__ cnt,
                                                     int* __restrict__ rowptr,
                                                     int* __restrict__ tot,
                                                     float* __restrict__ dinv,
                                                     float* __restrict__ c,
                                                     const int* __restrict__ batch, int n) {
    __shared__ int swave[16];
    int t = threadIdx.x;
    int lane = t & 63, wave = t >> 6;
    int i = blockIdx.x * 1024 + t;
    // coalesced zero of c rows [blockIdx*1024, +1024) — replaces a 10.24MB memset
    {
        size_t f4base = (size_t)blockIdx.x * 1024 * 16;  // 16 float4 per 64-float row
        size_t f4lim = (size_t)n * 16;
        float4 z = make_float4(0.f, 0.f, 0.f, 0.f);
#pragma unroll
        for (int q = 0; q < 16; ++q) {
            size_t idx = f4base + (size_t)q * 1024 + t;
            if (idx < f4lim) ((float4*)c)[idx] = z;
        }
    }
    int orig = (i < n) ? cnt[i] : 0;
    int v = orig;
#pragma unroll
    for (int off = 1; off < 64; off <<= 1) {
        int u = __shfl_up(v, off, 64);
        if (lane >= off) v += u;
    }
    if (lane == 63) swave[wave] = v;
    __syncthreads();  // orders c-zeroing before the slot store below too
    if (wave == 0) {
        int wv = (lane < 16) ? swave[lane] : 0;
#pragma unroll
        for (int off = 1; off < 16; off <<= 1) {
            int u = __shfl_up(wv, off, 64);
            if (lane >= off) wv += u;
        }
        if (lane < 16) swave[lane] = wv;
    }
    if (i < n) {
        float dv = rsqrtf((float)(orig + 1));  // deg = in-deg + self loop
        dinv[i] = dv;
        c[(size_t)i * N_GRAPHS + batch[i]] = dv * dv;  // self-loop contribution
    }
    __syncthreads();
    int incl = v + ((wave > 0) ? swave[wave - 1] : 0);
    if (i < n) rowptr[i] = incl - orig;  // chunk-local exclusive
    if (t == 1023) tot[blockIdx.x] = incl;
}

// phase B: add chunk offsets (<=40 totals: serial per-block prefix is cheap)
__global__ __launch_bounds__(1024) void scanB_kernel(int* __restrict__ rowptr,
                                                     const int* __restrict__ tot,
                                                     int n, int nchunks) {
    __shared__ int soff;
    int b = blockIdx.x, t = threadIdx.x;
    if (t == 0) {
        int o = 0;
        for (int j = 0; j < b; ++j) o += tot[j];
        soff = o;
    }
    __syncthreads();
    int i = b * 1024 + t;
    if (i < n) rowptr[i] += soff;
    if (b == 0 && t == 0) {
        int o = 0;
        for (int j = 0; j < nchunks; ++j) o += tot[j];
        rowptr[n] = o;
    }
}

// scatter col only (4B — w is recomputed in agg from L2-resident dinv), and
// accumulate the edge term of c: c[src][batch[dst]] += w
__global__ void fill_kernel(const int* __restrict__ src, const int* __restrict__ dst,
                            const int* __restrict__ rowptr, const int* __restrict__ rank,
                            int* __restrict__ col,
                            const float* __restrict__ dinv,
                            float* __restrict__ c, const int* __restrict__ batch, int E) {
    int e = blockIdx.x * blockDim.x + threadIdx.x;
    if (e < E) {
        int s = src[e], d = dst[e];
        int pos = rowptr[d] + rank[e];
        col[pos] = s;
        float w = dinv[s] * dinv[d];
        atomicAdd(&c[(size_t)s * N_GRAPHS + batch[d]], w);
    }
}

// ---------------- MFMA fp16 GEMM: hb[M x 128](fp16) = fp16(A) @ fp16(W) ----------
// 64-row x 128-col block, 4 waves each 32x64. fp32->fp16 conversion fused into
// LDS staging. LDS rows padded to 136 fp16 (68 dw): frag reads are 2-way max.
// Fragment layouts (m89/m120-verified, dtype-independent): A[m=lane&15][k=quad*8+j],
// B[k=quad*8+j][n=lane&15] (W transposed in LDS), C/D col=lane&15, row=quad*4+reg.

#define GBM 64

__global__ __launch_bounds__(256) void mfma_gemm_kernel(const float* __restrict__ A,
                                                        const float* __restrict__ W,
                                                        uint32* __restrict__ hb, int M) {
    __shared__ uint32 lds[64 * 68 + 128 * 68];  // As 17408B + Wt 34816B = 52224B
    uint32* As = lds;             // [64 rows][68 dw]
    uint32* Wt = lds + 64 * 68;   // [128 n][68 dw] — W transposed
    int tid = threadIdx.x;
    int row0 = blockIdx.x * GBM;

    // stage A tile: 64x128 fp32 -> fp16 (2048 float4, 8/thread, coalesced)
#pragma unroll
    for (int j = 0; j < 8; ++j) {
        int idx = tid + j * 256;
        int r = idx >> 5, c4 = idx & 31;
        float4 v = make_float4(0.f, 0.f, 0.f, 0.f);
        if (row0 + r < M) v = *(const float4*)&A[(size_t)(row0 + r) * D + c4 * 4];
        As[r * 68 + c4 * 2 + 0] = h2pair(v.x, v.y);
        As[r * 68 + c4 * 2 + 1] = h2pair(v.z, v.w);
    }
    // stage W^T: thread owns column n, half the k range (lane-coalesced global reads)
    {
        int nn = tid & 127, half = tid >> 7;
        int kbase = half * 64;
#pragma unroll
        for (int kk = 0; kk < 64; kk += 2) {
            float v0 = W[(size_t)(kbase + kk) * D + nn];
            float v1 = W[(size_t)(kbase + kk + 1) * D + nn];
            Wt[nn * 68 + ((kbase + kk) >> 1)] = h2pair(v0, v1);
        }
    }
    __syncthreads();

    int wave = tid >> 6, lane = tid & 63;
    int quad = lane >> 4, l16 = lane & 15;
    int wr = (wave & 1) * 32;   // wave row base (2 m-tiles)
    int wc = (wave >> 1) * 64;  // wave col base (4 n-tiles)
    f32x4 acc[2][4];
#pragma unroll
    for (int mi = 0; mi < 2; ++mi)
#pragma unroll
        for (int ni = 0; ni < 4; ++ni) acc[mi][ni] = (f32x4){0.f, 0.f, 0.f, 0.f};

#pragma unroll
    for (int ks = 0; ks < 4; ++ks) {
        int kd = ks * 16 + quad * 4;  // dword offset of k0 + quad*8 fp16
        f16x8 a0 = *(f16x8*)&As[(wr + l16) * 68 + kd];
        f16x8 a1 = *(f16x8*)&As[(wr + 16 + l16) * 68 + kd];
        f16x8 b0 = *(f16x8*)&Wt[(wc + l16) * 68 + kd];
        f16x8 b1 = *(f16x8*)&Wt[(wc + 16 + l16) * 68 + kd];
        f16x8 b2 = *(f16x8*)&Wt[(wc + 32 + l16) * 68 + kd];
        f16x8 b3 = *(f16x8*)&Wt[(wc + 48 + l16) * 68 + kd];
        acc[0][0] = __builtin_amdgcn_mfma_f32_16x16x32_f16(a0, b0, acc[0][0], 0, 0, 0);
        acc[0][1] = __builtin_amdgcn_mfma_f32_16x16x32_f16(a0, b1, acc[0][1], 0, 0, 0);
        acc[0][2] = __builtin_amdgcn_mfma_f32_16x16x32_f16(a0, b2, acc[0][2], 0, 0, 0);
        acc[0][3] = __builtin_amdgcn_mfma_f32_16x16x32_f16(a0, b3, acc[0][3], 0, 0, 0);
        acc[1][0] = __builtin_amdgcn_mfma_f32_16x16x32_f16(a1, b0, acc[1][0], 0, 0, 0);
        acc[1][1] = __builtin_amdgcn_mfma_f32_16x16x32_f16(a1, b1, acc[1][1], 0, 0, 0);
        acc[1][2] = __builtin_amdgcn_mfma_f32_16x16x32_f16(a1, b2, acc[1][2], 0, 0, 0);
        acc[1][3] = __builtin_amdgcn_mfma_f32_16x16x32_f16(a1, b3, acc[1][3], 0, 0, 0);
    }
    __syncthreads();  // done reading As/Wt; reuse As region as C staging [64][128] fp16

    unsigned short* cs = (unsigned short*)lds;
#pragma unroll
    for (int mi = 0; mi < 2; ++mi)
#pragma unroll
        for (int ni = 0; ni < 4; ++ni)
#pragma unroll
            for (int r = 0; r < 4; ++r) {
                int row = wr + mi * 16 + quad * 4 + r;
                int col = wc + ni * 16 + l16;
                cs[row * 128 + col] =
                    __builtin_bit_cast(unsigned short, (_Float16)acc[mi][ni][r]);
            }
    __syncthreads();
    // coalesced write-out: 64 rows x 16 uint4; C-staging row = 128 fp16 = 64 dwords
#pragma unroll
    for (int j = 0; j < 4; ++j) {
        int idx = tid + j * 256;
        int r = idx >> 4, q = idx & 15;
        if (row0 + r < M)
            *(uint4*)&hb[(size_t)(row0 + r) * 64 + q * 4] = *(uint4*)&lds[r * 64 + q * 4];
    }
}

// ---------------- aggregation (gather over CSR) + bias + ReLU -> fp16 H1 --------
// Full fp16 rows (R10's feature-split doubled the edge-stream work for no gather
// win — reverted). 32-lane group per node, uint2 (8B = 4 fp16) per lane = 256B
// row/load. Unroll x16 (mean degree 16): up to 16 independent gathers in flight.

__global__ __launch_bounds__(128) void agg_kernel(const uint32* __restrict__ hb,
                                                  const int* __restrict__ rowptr,
                                                  const int* __restrict__ col,
                                                  const float* __restrict__ dinv,
                                                  const float* __restrict__ bias,
                                                  uint32* __restrict__ h1, int n) {
    int tid = threadIdx.x;
    int lane32 = tid & 31;   // features 4*lane32 .. 4*lane32+3
    int slot = tid >> 5;     // 0..3
    int node = blockIdx.x * 4 + slot;
    if (node >= n) return;
    const uint2* __restrict__ h2 = (const uint2*)hb;  // 32 uint2 per row

    float di = dinv[node];
    float ws = di * di;
    uint2 su = h2[(size_t)node * 32 + lane32];
    float a0 = ws * hl(su.x), a1 = ws * hh(su.x);
    float a2 = ws * hl(su.y), a3 = ws * hh(su.y);

    int k = rowptr[node], end = rowptr[node + 1];
    for (; k + 16 <= end; k += 16) {
        uint2 v[16];
        float w[16];
#pragma unroll
        for (int j = 0; j < 16; ++j) {
            int s = col[k + j];
            w[j] = dinv[s] * di;
            v[j] = h2[(size_t)s * 32 + lane32];
        }
#pragma unroll
        for (int j = 0; j < 16; ++j) {
            a0 = fmaf(w[j], hl(v[j].x), a0);
            a1 = fmaf(w[j], hh(v[j].x), a1);
            a2 = fmaf(w[j], hl(v[j].y), a2);
            a3 = fmaf(w[j], hh(v[j].y), a3);
        }
    }
    if (k + 8 <= end) {
        uint2 v[8];
        float w[8];
#pragma unroll
        for (int j = 0; j < 8; ++j) {
            int s = col[k + j];
            w[j] = dinv[s] * di;
            v[j] = h2[(size_t)s * 32 + lane32];
        }
#pragma unroll
        for (int j = 0; j < 8; ++j) {
            a0 = fmaf(w[j], hl(v[j].x), a0);
            a1 = fmaf(w[j], hh(v[j].x), a1);
            a2 = fmaf(w[j], hl(v[j].y), a2);
            a3 = fmaf(w[j], hh(v[j].y), a3);
        }
        k += 8;
    }
    for (; k < end; ++k) {
        int s = col[k];
        float w = dinv[s] * di;
        uint2 v = h2[(size_t)s * 32 + lane32];
        a0 = fmaf(w, hl(v.x), a0);
        a1 = fmaf(w, hh(v.x), a1);
        a2 = fmaf(w, hl(v.y), a2);
        a3 = fmaf(w, hh(v.y), a3);
    }

    float4 b4 = ((const float4*)bias)[lane32];
    a0 = fmaxf(a0 + b4.x, 0.f);
    a1 = fmaxf(a1 + b4.y, 0.f);
    a2 = fmaxf(a2 + b4.z, 0.f);
    a3 = fmaxf(a3 + b4.w, 0.f);
    uint2 o;
    o.x = h2pair(a0, a1);
    o.y = h2pair(a2, a3);
    ((uint2*)h1)[(size_t)node * 32 + lane32] = o;
}

// ---------------- pooled layer 2: out = rinv * (c^T H1) W2 + b2 ----------------

// Gp partials: Ppart[b][g][f] = sum_{j in block b's range} c[j][g] * H1[j][f]
#define GP_NB 128
#define GP_T 16

__global__ __launch_bounds__(256) void gp_kernel(const float* __restrict__ c,
                                                 const uint32* __restrict__ H1,
                                                 float* __restrict__ Ppart, int n) {
    __shared__ float sc[GP_T][N_GRAPHS];
    __shared__ uint32 sh[GP_T][64];  // fp16 pairs: 128 feats = 64 dwords
    int t = threadIdx.x;
    int b = blockIdx.x;
    int jpb = (n + GP_NB - 1) / GP_NB;
    int j0 = b * jpb;
    int j1 = min(j0 + jpb, n);
    int g0 = (t & 7) * 8;    // 8 graphs per thread
    int f0 = (t >> 3) * 4;   // 4 feats per thread (dwords f0/2, f0/2+1)
    float acc[8][4];
#pragma unroll
    for (int a = 0; a < 8; ++a)
#pragma unroll
        for (int q = 0; q < 4; ++q) acc[a][q] = 0.f;

    for (int jt = j0; jt < j1; jt += GP_T) {
        int cnt = min(GP_T, j1 - jt);
        // stage c tile: GP_T x 64 floats = 256 float4, 1/thread
        {
            int r = t >> 4, q = t & 15;
            float4 v = (r < cnt) ? *(const float4*)&c[(size_t)(jt + r) * N_GRAPHS + q * 4]
                                 : make_float4(0.f, 0.f, 0.f, 0.f);
            *(float4*)&sc[r][q * 4] = v;
        }
        // stage H1 fp16 tile: GP_T rows x 16 uint4 = 256, 1/thread
        {
            int r = t >> 4, q = t & 15;
            uint4 v = make_uint4(0, 0, 0, 0);
            if (r < cnt) v = *(const uint4*)&H1[(size_t)(jt + r) * 64 + q * 4];
            *(uint4*)&sh[r][q * 4] = v;
        }
        __syncthreads();
#pragma unroll
        for (int r = 0; r < GP_T; ++r) {  // zero-padded rows contribute 0
            float cw[8], hv[4];
            *(float4*)&cw[0] = *(float4*)&sc[r][g0];
            *(float4*)&cw[4] = *(float4*)&sc[r][g0 + 4];
            uint32 u0 = sh[r][f0 >> 1], u1 = sh[r][(f0 >> 1) + 1];
            hv[0] = hl(u0); hv[1] = hh(u0); hv[2] = hl(u1); hv[3] = hh(u1);
#pragma unroll
            for (int a = 0; a < 8; ++a)
#pragma unroll
                for (int q = 0; q < 4; ++q) acc[a][q] = fmaf(cw[a], hv[q], acc[a][q]);
        }
        __syncthreads();
    }
    float* P = &Ppart[(size_t)b * N_GRAPHS * D];
#pragma unroll
    for (int a = 0; a < 8; ++a)
        *(float4*)&P[(size_t)(g0 + a) * D + f0] =
            make_float4(acc[a][0], acc[a][1], acc[a][2], acc[a][3]);
}

// epilogue: out[g][f] = rinv_g * sum_k (sum_b Ppart[b][g][k]) * W2[k][f] + b2[f]
// rinv computed in-block via binary search on sorted batch (graph_count folded in)
__global__ __launch_bounds__(128) void out_kernel(const float* __restrict__ Ppart,
                                                  const float* __restrict__ W2,
                                                  const float* __restrict__ b2,
                                                  const int* __restrict__ batch, int n,
                                                  float* __restrict__ out) {
    __shared__ float gs[D];
    __shared__ float srinv;
    int g = blockIdx.x, f = threadIdx.x;
    if (f == 0) {
        int lo = 0, hi = n;
        while (lo < hi) { int mid = (lo + hi) >> 1; if (batch[mid] < g) lo = mid + 1; else hi = mid; }
        int lb = lo;
        int g1 = g + 1;
        lo = 0; hi = n;
        while (lo < hi) { int mid = (lo + hi) >> 1; if (batch[mid] < g1) lo = mid + 1; else hi = mid; }
        int cg = lo - lb;
        srinv = (cg > 0) ? 1.0f / (float)cg : 0.0f;
    }
    float s = 0.f;
    for (int b = 0; b < GP_NB; ++b) s += Ppart[((size_t)b * N_GRAPHS + g) * D + f];
    gs[f] = s;
    __syncthreads();
    float acc = 0.f;
#pragma unroll 8
    for (int k = 0; k < D; ++k) acc = fmaf(gs[k], W2[k * D + f], acc);
    float r = srinv;
    out[g * D + f] = (r > 0.f) ? fmaf(acc, r, b2[f]) : 0.f;  // empty graph -> 0 (matches ref)
}

// ---------------- launcher ----------------

extern "C" void kernel_launch(void* const* d_in, const int* in_sizes, int n_in,
                              void* d_out, int out_size, void* d_ws, size_t ws_size,
                              hipStream_t stream) {
    const float* x  = (const float*)d_in[0];
    const int*   ei = (const int*)d_in[1];
    const int*   batch = (const int*)d_in[2];
    const float* W1 = (const float*)d_in[3];
    const float* b1 = (const float*)d_in[4];
    const float* W2 = (const float*)d_in[5];
    const float* b2 = (const float*)d_in[6];
    float* out = (float*)d_out;

    const int n = in_sizes[2];       // 40000 nodes
    const int E = in_sizes[1] / 2;   // 640000 edges
    const int* src = ei;             // edge_index[0] = message sources
    const int* dst = ei + E;         // edge_index[1] = aggregation targets

    // workspace carve-up (256B aligned)
    char* ws = (char*)d_ws;
    size_t off = 0;
    auto carve = [&](size_t bytes) {
        size_t o = off;
        off = (off + bytes + 255) & ~(size_t)255;
        return (void*)(ws + o);
    };
    int*    cnt    = (int*)carve((size_t)n * 4);
    int*    rowptr = (int*)carve((size_t)(n + 1) * 4);
    float*  dinv   = (float*)carve((size_t)n * 4);
    int*    col    = (int*)carve((size_t)E * 4);                 // CSR col (2.56MB)
    uint32* hb     = (uint32*)carve((size_t)n * D * 2);          // fp16 feature rows (10.24MB)
    uint32* h1     = (uint32*)carve((size_t)n * D * 2);          // fp16 H1 rows (10.24MB)
    float*  c      = (float*)carve((size_t)n * N_GRAPHS * 4);    // pooled coeffs (10.24MB)
    int*    tot    = (int*)carve(64 * 4);
    // aliases into hb (10.24MB): rank (2.56MB, dead after fill — gemm1 writes hb after);
    // Ppart (4MB, written by gp after agg's last read of hb)
    int*    rank   = (int*)hb;
    float*  Ppart  = (float*)hb;
    (void)ws_size;

    const int nchunks = (n + 1023) >> 10;

    // zero-init (ws is poisoned 0xAA before every call); c zeroing fused into scanA
    hipMemsetAsync(cnt, 0, (size_t)n * 4, stream);

    // CSR build + pooled-coefficient matrix c (shared by both layers)
    count_rank_kernel<<<(E + 255) / 256, 256, 0, stream>>>(dst, cnt, rank, E);
    scanA_kernel<<<nchunks, 1024, 0, stream>>>(cnt, rowptr, tot, dinv, c, batch, n);
    scanB_kernel<<<nchunks, 1024, 0, stream>>>(rowptr, tot, n, nchunks);
    fill_kernel<<<(E + 255) / 256, 256, 0, stream>>>(src, dst, rowptr, rank, col, dinv, c, batch, E);

    // layer 1: hb = fp16(x @ W1) via MFMA ; agg + b1 + ReLU -> h1 (fp16)
    mfma_gemm_kernel<<<(n + GBM - 1) / GBM, 256, 0, stream>>>(x, W1, hb, n);
    agg_kernel<<<(n + 3) / 4, 128, 0, stream>>>(hb, rowptr, col, dinv, b1, h1, n);

    // layer 2 + pool, algebraically fused: out = rinv * (c^T H1) W2 + b2
    gp_kernel<<<GP_NB, 256, 0, stream>>>(c, h1, Ppart, n);
    out_kernel<<<N_GRAPHS, 128, 0, stream>>>(Ppart, W2, b2, batch, n, out);
}

// Round 13
// 224.314 us; speedup vs baseline: 1.1015x; 1.0728x over previous
//
#include <hip/hip_runtime.h>

#define D 128
#define N_GRAPHS 64

typedef unsigned int uint32;
typedef __attribute__((ext_vector_type(8))) _Float16 f16x8;
typedef __attribute__((ext_vector_type(4))) float f32x4;

// fp16 helpers: dword holds 2 fp16 (low = elem 2i, high = elem 2i+1); RNE cvt
__device__ __forceinline__ float hl(uint32 u) {
    return (float)__builtin_bit_cast(_Float16, (unsigned short)(u & 0xFFFF));
}
__device__ __forceinline__ float hh(uint32 u) {
    return (float)__builtin_bit_cast(_Float16, (unsigned short)(u >> 16));
}
__device__ __forceinline__ uint32 h2pair(float a, float b) {
    unsigned short ua = __builtin_bit_cast(unsigned short, (_Float16)a);
    unsigned short ub = __builtin_bit_cast(unsigned short, (_Float16)b);
    return (uint32)ua | ((uint32)ub << 16);
}

// ---------------- CSR build ----------------

// count in-degree AND capture each edge's rank among its dst's edges.
// (R8 lesson: folding this atomic into fill puts the RMW return on the
// scatter's critical path — fill went 40 -> 67 us. Keep it split.)
__global__ void count_rank_kernel(const int* __restrict__ dst, int* __restrict__ cnt,
                                  int* __restrict__ rank, int E) {
    int e = blockIdx.x * blockDim.x + threadIdx.x;
    if (e < E) rank[e] = atomicAdd(&cnt[dst[e]], 1);
}

// parallel scan, phase A. Fused: dinv; coalesced zeroing of this block's c rows
// + self-loop term c[i][batch[i]] = dinv_i^2 (ordered by the block barrier).
__global__ __launch_bounds__(1024) void scanA_kernel(const int* __restrict__ cnt,
                                                     int* __restrict__ rowptr,
                                                     int* __restrict__ tot,
                                                     float* __restrict__ dinv,
                                                     float* __restrict__ c,
                                                     const int* __restrict__ batch, int n) {
    __shared__ int swave[16];
    int t = threadIdx.x;
    int lane = t & 63, wave = t >> 6;
    int i = blockIdx.x * 1024 + t;
    // coalesced zero of c rows [blockIdx*1024, +1024) — replaces a 10.24MB memset
    {
        size_t f4base = (size_t)blockIdx.x * 1024 * 16;  // 16 float4 per 64-float row
        size_t f4lim = (size_t)n * 16;
        float4 z = make_float4(0.f, 0.f, 0.f, 0.f);
#pragma unroll
        for (int q = 0; q < 16; ++q) {
            size_t idx = f4base + (size_t)q * 1024 + t;
            if (idx < f4lim) ((float4*)c)[idx] = z;
        }
    }
    int orig = (i < n) ? cnt[i] : 0;
    int v = orig;
#pragma unroll
    for (int off = 1; off < 64; off <<= 1) {
        int u = __shfl_up(v, off, 64);
        if (lane >= off) v += u;
    }
    if (lane == 63) swave[wave] = v;
    __syncthreads();  // orders c-zeroing before the slot store below too
    if (wave == 0) {
        int wv = (lane < 16) ? swave[lane] : 0;
#pragma unroll
        for (int off = 1; off < 16; off <<= 1) {
            int u = __shfl_up(wv, off, 64);
            if (lane >= off) wv += u;
        }
        if (lane < 16) swave[lane] = wv;
    }
    if (i < n) {
        float dv = rsqrtf((float)(orig + 1));  // deg = in-deg + self loop
        dinv[i] = dv;
        c[(size_t)i * N_GRAPHS + batch[i]] = dv * dv;  // self-loop contribution
    }
    __syncthreads();
    int incl = v + ((wave > 0) ? swave[wave - 1] : 0);
    if (i < n) rowptr[i] = incl - orig;  // chunk-local exclusive
    if (t == 1023) tot[blockIdx.x] = incl;
}

// phase B: add chunk offsets (<=40 totals: serial per-block prefix is cheap)
__global__ __launch_bounds__(1024) void scanB_kernel(int* __restrict__ rowptr,
                                                     const int* __restrict__ tot,
                                                     int n, int nchunks) {
    __shared__ int soff;
    int b = blockIdx.x, t = threadIdx.x;
    if (t == 0) {
        int o = 0;
        for (int j = 0; j < b; ++j) o += tot[j];
        soff = o;
    }
    __syncthreads();
    int i = b * 1024 + t;
    if (i < n) rowptr[i] += soff;
    if (b == 0 && t == 0) {
        int o = 0;
        for (int j = 0; j < nchunks; ++j) o += tot[j];
        rowptr[n] = o;
    }
}

// scatter col only (4B — w is recomputed in agg from L2-resident dinv), and
// accumulate the edge term of c: c[src][batch[dst]] += w
__global__ void fill_kernel(const int* __restrict__ src, const int* __restrict__ dst,
                            const int* __restrict__ rowptr, const int* __restrict__ rank,
                            int* __restrict__ col,
                            const float* __restrict__ dinv,
                            float* __restrict__ c, const int* __restrict__ batch, int E) {
    int e = blockIdx.x * blockDim.x + threadIdx.x;
    if (e < E) {
        int s = src[e], d = dst[e];
        int pos = rowptr[d] + rank[e];
        col[pos] = s;
        float w = dinv[s] * dinv[d];
        atomicAdd(&c[(size_t)s * N_GRAPHS + batch[d]], w);
    }
}

// ---------------- MFMA fp16 GEMM: hb[M x 128](fp16) = fp16(A) @ fp16(W) ----------
// 64-row x 128-col block, 4 waves each 32x64. fp32->fp16 conversion fused into
// LDS staging. LDS rows padded to 136 fp16 (68 dw): frag reads are 2-way max.
// Fragment layouts (m89/m120-verified, dtype-independent): A[m=lane&15][k=quad*8+j],
// B[k=quad*8+j][n=lane&15] (W transposed in LDS), C/D col=lane&15, row=quad*4+reg.

#define GBM 64

__global__ __launch_bounds__(256) void mfma_gemm_kernel(const float* __restrict__ A,
                                                        const float* __restrict__ W,
                                                        uint32* __restrict__ hb, int M) {
    __shared__ uint32 lds[64 * 68 + 128 * 68];  // As 17408B + Wt 34816B = 52224B
    uint32* As = lds;             // [64 rows][68 dw]
    uint32* Wt = lds + 64 * 68;   // [128 n][68 dw] — W transposed
    int tid = threadIdx.x;
    int row0 = blockIdx.x * GBM;

    // stage A tile: 64x128 fp32 -> fp16 (2048 float4, 8/thread, coalesced)
#pragma unroll
    for (int j = 0; j < 8; ++j) {
        int idx = tid + j * 256;
        int r = idx >> 5, c4 = idx & 31;
        float4 v = make_float4(0.f, 0.f, 0.f, 0.f);
        if (row0 + r < M) v = *(const float4*)&A[(size_t)(row0 + r) * D + c4 * 4];
        As[r * 68 + c4 * 2 + 0] = h2pair(v.x, v.y);
        As[r * 68 + c4 * 2 + 1] = h2pair(v.z, v.w);
    }
    // stage W^T: thread owns column n, half the k range (lane-coalesced global reads)
    {
        int nn = tid & 127, half = tid >> 7;
        int kbase = half * 64;
#pragma unroll
        for (int kk = 0; kk < 64; kk += 2) {
            float v0 = W[(size_t)(kbase + kk) * D + nn];
            float v1 = W[(size_t)(kbase + kk + 1) * D + nn];
            Wt[nn * 68 + ((kbase + kk) >> 1)] = h2pair(v0, v1);
        }
    }
    __syncthreads();

    int wave = tid >> 6, lane = tid & 63;
    int quad = lane >> 4, l16 = lane & 15;
    int wr = (wave & 1) * 32;   // wave row base (2 m-tiles)
    int wc = (wave >> 1) * 64;  // wave col base (4 n-tiles)
    f32x4 acc[2][4];
#pragma unroll
    for (int mi = 0; mi < 2; ++mi)
#pragma unroll
        for (int ni = 0; ni < 4; ++ni) acc[mi][ni] = (f32x4){0.f, 0.f, 0.f, 0.f};

#pragma unroll
    for (int ks = 0; ks < 4; ++ks) {
        int kd = ks * 16 + quad * 4;  // dword offset of k0 + quad*8 fp16
        f16x8 a0 = *(f16x8*)&As[(wr + l16) * 68 + kd];
        f16x8 a1 = *(f16x8*)&As[(wr + 16 + l16) * 68 + kd];
        f16x8 b0 = *(f16x8*)&Wt[(wc + l16) * 68 + kd];
        f16x8 b1 = *(f16x8*)&Wt[(wc + 16 + l16) * 68 + kd];
        f16x8 b2 = *(f16x8*)&Wt[(wc + 32 + l16) * 68 + kd];
        f16x8 b3 = *(f16x8*)&Wt[(wc + 48 + l16) * 68 + kd];
        acc[0][0] = __builtin_amdgcn_mfma_f32_16x16x32_f16(a0, b0, acc[0][0], 0, 0, 0);
        acc[0][1] = __builtin_amdgcn_mfma_f32_16x16x32_f16(a0, b1, acc[0][1], 0, 0, 0);
        acc[0][2] = __builtin_amdgcn_mfma_f32_16x16x32_f16(a0, b2, acc[0][2], 0, 0, 0);
        acc[0][3] = __builtin_amdgcn_mfma_f32_16x16x32_f16(a0, b3, acc[0][3], 0, 0, 0);
        acc[1][0] = __builtin_amdgcn_mfma_f32_16x16x32_f16(a1, b0, acc[1][0], 0, 0, 0);
        acc[1][1] = __builtin_amdgcn_mfma_f32_16x16x32_f16(a1, b1, acc[1][1], 0, 0, 0);
        acc[1][2] = __builtin_amdgcn_mfma_f32_16x16x32_f16(a1, b2, acc[1][2], 0, 0, 0);
        acc[1][3] = __builtin_amdgcn_mfma_f32_16x16x32_f16(a1, b3, acc[1][3], 0, 0, 0);
    }
    __syncthreads();  // done reading As/Wt; reuse As region as C staging [64][128] fp16

    unsigned short* cs = (unsigned short*)lds;
#pragma unroll
    for (int mi = 0; mi < 2; ++mi)
#pragma unroll
        for (int ni = 0; ni < 4; ++ni)
#pragma unroll
            for (int r = 0; r < 4; ++r) {
                int row = wr + mi * 16 + quad * 4 + r;
                int col = wc + ni * 16 + l16;
                cs[row * 128 + col] =
                    __builtin_bit_cast(unsigned short, (_Float16)acc[mi][ni][r]);
            }
    __syncthreads();
    // coalesced write-out: 64 rows x 16 uint4; C-staging row = 128 fp16 = 64 dwords
#pragma unroll
    for (int j = 0; j < 4; ++j) {
        int idx = tid + j * 256;
        int r = idx >> 4, q = idx & 15;
        if (row0 + r < M)
            *(uint4*)&hb[(size_t)(row0 + r) * 64 + q * 4] = *(uint4*)&lds[r * 64 + q * 4];
    }
}

// ---------------- aggregation (gather over CSR) + bias + ReLU -> fp16 H1 --------
// fp16 rows: 32-lane group per node, uint2 (8B = 4 fp16) per lane = 256B row/load.
// Unroll x8: the R11 x16 attempt raised VGPR (v[16]+w[16] ~48 regs live) and cost
// occupancy — regressed. x8 is the measured optimum for this latency-bound loop.

__global__ __launch_bounds__(128) void agg_kernel(const uint32* __restrict__ hb,
                                                  const int* __restrict__ rowptr,
                                                  const int* __restrict__ col,
                                                  const float* __restrict__ dinv,
                                                  const float* __restrict__ bias,
                                                  uint32* __restrict__ h1, int n) {
    int tid = threadIdx.x;
    int lane32 = tid & 31;   // features 4*lane32 .. 4*lane32+3
    int slot = tid >> 5;     // 0..3
    int node = blockIdx.x * 4 + slot;
    if (node >= n) return;
    const uint2* __restrict__ h2 = (const uint2*)hb;  // 32 uint2 per row

    float di = dinv[node];
    float ws = di * di;
    uint2 su = h2[(size_t)node * 32 + lane32];
    float a0 = ws * hl(su.x), a1 = ws * hh(su.x);
    float a2 = ws * hl(su.y), a3 = ws * hh(su.y);

    int k = rowptr[node], end = rowptr[node + 1];
    for (; k + 8 <= end; k += 8) {
        uint2 v[8];
        float w[8];
#pragma unroll
        for (int j = 0; j < 8; ++j) {
            int s = col[k + j];
            w[j] = dinv[s] * di;
            v[j] = h2[(size_t)s * 32 + lane32];
        }
#pragma unroll
        for (int j = 0; j < 8; ++j) {
            a0 = fmaf(w[j], hl(v[j].x), a0);
            a1 = fmaf(w[j], hh(v[j].x), a1);
            a2 = fmaf(w[j], hl(v[j].y), a2);
            a3 = fmaf(w[j], hh(v[j].y), a3);
        }
    }
    for (; k < end; ++k) {
        int s = col[k];
        float w = dinv[s] * di;
        uint2 v = h2[(size_t)s * 32 + lane32];
        a0 = fmaf(w, hl(v.x), a0);
        a1 = fmaf(w, hh(v.x), a1);
        a2 = fmaf(w, hl(v.y), a2);
        a3 = fmaf(w, hh(v.y), a3);
    }

    float4 b4 = ((const float4*)bias)[lane32];
    a0 = fmaxf(a0 + b4.x, 0.f);
    a1 = fmaxf(a1 + b4.y, 0.f);
    a2 = fmaxf(a2 + b4.z, 0.f);
    a3 = fmaxf(a3 + b4.w, 0.f);
    uint2 o;
    o.x = h2pair(a0, a1);
    o.y = h2pair(a2, a3);
    ((uint2*)h1)[(size_t)node * 32 + lane32] = o;
}

// ---------------- pooled layer 2: out = rinv * (c^T H1) W2 + b2 ----------------

// Gp partials: Ppart[b][g][f] = sum_{j in block b's range} c[j][g] * H1[j][f]
// GP_NB=256: one block per CU — 128 left half the GPU idle (R11 regression).
#define GP_NB 256
#define GP_T 16

__global__ __launch_bounds__(256) void gp_kernel(const float* __restrict__ c,
                                                 const uint32* __restrict__ H1,
                                                 float* __restrict__ Ppart, int n) {
    __shared__ float sc[GP_T][N_GRAPHS];
    __shared__ uint32 sh[GP_T][64];  // fp16 pairs: 128 feats = 64 dwords
    int t = threadIdx.x;
    int b = blockIdx.x;
    int jpb = (n + GP_NB - 1) / GP_NB;
    int j0 = b * jpb;
    int j1 = min(j0 + jpb, n);
    int g0 = (t & 7) * 8;    // 8 graphs per thread
    int f0 = (t >> 3) * 4;   // 4 feats per thread (dwords f0/2, f0/2+1)
    float acc[8][4];
#pragma unroll
    for (int a = 0; a < 8; ++a)
#pragma unroll
        for (int q = 0; q < 4; ++q) acc[a][q] = 0.f;

    for (int jt = j0; jt < j1; jt += GP_T) {
        int cnt = min(GP_T, j1 - jt);
        // stage c tile: GP_T x 64 floats = 256 float4, 1/thread
        {
            int r = t >> 4, q = t & 15;
            float4 v = (r < cnt) ? *(const float4*)&c[(size_t)(jt + r) * N_GRAPHS + q * 4]
                                 : make_float4(0.f, 0.f, 0.f, 0.f);
            *(float4*)&sc[r][q * 4] = v;
        }
        // stage H1 fp16 tile: GP_T rows x 16 uint4 = 256, 1/thread
        {
            int r = t >> 4, q = t & 15;
            uint4 v = make_uint4(0, 0, 0, 0);
            if (r < cnt) v = *(const uint4*)&H1[(size_t)(jt + r) * 64 + q * 4];
            *(uint4*)&sh[r][q * 4] = v;
        }
        __syncthreads();
#pragma unroll
        for (int r = 0; r < GP_T; ++r) {  // zero-padded rows contribute 0
            float cw[8], hv[4];
            *(float4*)&cw[0] = *(float4*)&sc[r][g0];
            *(float4*)&cw[4] = *(float4*)&sc[r][g0 + 4];
            uint32 u0 = sh[r][f0 >> 1], u1 = sh[r][(f0 >> 1) + 1];
            hv[0] = hl(u0); hv[1] = hh(u0); hv[2] = hl(u1); hv[3] = hh(u1);
#pragma unroll
            for (int a = 0; a < 8; ++a)
#pragma unroll
                for (int q = 0; q < 4; ++q) acc[a][q] = fmaf(cw[a], hv[q], acc[a][q]);
        }
        __syncthreads();
    }
    float* P = &Ppart[(size_t)b * N_GRAPHS * D];
#pragma unroll
    for (int a = 0; a < 8; ++a)
        *(float4*)&P[(size_t)(g0 + a) * D + f0] =
            make_float4(acc[a][0], acc[a][1], acc[a][2], acc[a][3]);
}

// epilogue: out[g][f] = rinv_g * sum_k (sum_b Ppart[b][g][k]) * W2[k][f] + b2[f]
// rinv computed in-block via binary search on sorted batch (graph_count folded in)
__global__ __launch_bounds__(128) void out_kernel(const float* __restrict__ Ppart,
                                                  const float* __restrict__ W2,
                                                  const float* __restrict__ b2,
                                                  const int* __restrict__ batch, int n,
                                                  float* __restrict__ out) {
    __shared__ float gs[D];
    __shared__ float srinv;
    int g = blockIdx.x, f = threadIdx.x;
    if (f == 0) {
        int lo = 0, hi = n;
        while (lo < hi) { int mid = (lo + hi) >> 1; if (batch[mid] < g) lo = mid + 1; else hi = mid; }
        int lb = lo;
        int g1 = g + 1;
        lo = 0; hi = n;
        while (lo < hi) { int mid = (lo + hi) >> 1; if (batch[mid] < g1) lo = mid + 1; else hi = mid; }
        int cg = lo - lb;
        srinv = (cg > 0) ? 1.0f / (float)cg : 0.0f;
    }
    float s = 0.f;
    for (int b = 0; b < GP_NB; ++b) s += Ppart[((size_t)b * N_GRAPHS + g) * D + f];
    gs[f] = s;
    __syncthreads();
    float acc = 0.f;
#pragma unroll 8
    for (int k = 0; k < D; ++k) acc = fmaf(gs[k], W2[k * D + f], acc);
    float r = srinv;
    out[g * D + f] = (r > 0.f) ? fmaf(acc, r, b2[f]) : 0.f;  // empty graph -> 0 (matches ref)
}

// ---------------- launcher ----------------

extern "C" void kernel_launch(void* const* d_in, const int* in_sizes, int n_in,
                              void* d_out, int out_size, void* d_ws, size_t ws_size,
                              hipStream_t stream) {
    const float* x  = (const float*)d_in[0];
    const int*   ei = (const int*)d_in[1];
    const int*   batch = (const int*)d_in[2];
    const float* W1 = (const float*)d_in[3];
    const float* b1 = (const float*)d_in[4];
    const float* W2 = (const float*)d_in[5];
    const float* b2 = (const float*)d_in[6];
    float* out = (float*)d_out;

    const int n = in_sizes[2];       // 40000 nodes
    const int E = in_sizes[1] / 2;   // 640000 edges
    const int* src = ei;             // edge_index[0] = message sources
    const int* dst = ei + E;         // edge_index[1] = aggregation targets

    // workspace carve-up (256B aligned)
    char* ws = (char*)d_ws;
    size_t off = 0;
    auto carve = [&](size_t bytes) {
        size_t o = off;
        off = (off + bytes + 255) & ~(size_t)255;
        return (void*)(ws + o);
    };
    int*    cnt    = (int*)carve((size_t)n * 4);
    int*    rowptr = (int*)carve((size_t)(n + 1) * 4);
    float*  dinv   = (float*)carve((size_t)n * 4);
    int*    col    = (int*)carve((size_t)E * 4);                 // CSR col (2.56MB)
    uint32* hb     = (uint32*)carve((size_t)n * D * 2);          // fp16 feature rows (10.24MB)
    uint32* h1     = (uint32*)carve((size_t)n * D * 2);          // fp16 H1 rows (10.24MB)
    float*  c      = (float*)carve((size_t)n * N_GRAPHS * 4);    // pooled coeffs (10.24MB)
    int*    tot    = (int*)carve(64 * 4);
    // aliases into hb (10.24MB): rank (2.56MB, dead after fill — gemm1 writes hb after);
    // Ppart (8MB, written by gp after agg's last read of hb)
    int*    rank   = (int*)hb;
    float*  Ppart  = (float*)hb;
    (void)ws_size;

    const int nchunks = (n + 1023) >> 10;

    // zero-init (ws is poisoned 0xAA before every call); c zeroing fused into scanA
    hipMemsetAsync(cnt, 0, (size_t)n * 4, stream);

    // CSR build + pooled-coefficient matrix c (shared by both layers)
    count_rank_kernel<<<(E + 255) / 256, 256, 0, stream>>>(dst, cnt, rank, E);
    scanA_kernel<<<nchunks, 1024, 0, stream>>>(cnt, rowptr, tot, dinv, c, batch, n);
    scanB_kernel<<<nchunks, 1024, 0, stream>>>(rowptr, tot, n, nchunks);
    fill_kernel<<<(E + 255) / 256, 256, 0, stream>>>(src, dst, rowptr, rank, col, dinv, c, batch, E);

    // layer 1: hb = fp16(x @ W1) via MFMA ; agg + b1 + ReLU -> h1 (fp16)
    mfma_gemm_kernel<<<(n + GBM - 1) / GBM, 256, 0, stream>>>(x, W1, hb, n);
    agg_kernel<<<(n + 3) / 4, 128, 0, stream>>>(hb, rowptr, col, dinv, b1, h1, n);

    // layer 2 + pool, algebraically fused: out = rinv * (c^T H1) W2 + b2
    gp_kernel<<<GP_NB, 256, 0, stream>>>(c, h1, Ppart, n);
    out_kernel<<<N_GRAPHS, 128, 0, stream>>>(Ppart, W2, b2, batch, n, out);
}